// Round 1
// baseline (723.905 us; speedup 1.0000x reference)
//
#include <hip/hip_runtime.h>
#include <hip/hip_bf16.h>
#include <hip/hip_cooperative_groups.h>

namespace cg = cooperative_groups;

#define NN 50000
#define NE 800000
#define HD 64
#define OD 16
#define CAP 64        // padded-CSR slots per node (mean deg = 16; P(>64) ~ 1e-18)
#define TILES 3125    // NN/16
#define AST 72        // LDS A/C row stride in u16 (144 B); 36 u32
#define SCATB 2048    // scatter blocks in k_pre
#define PSZ 6250      // NN / 8 partitions
#define LGRID 2048    // cooperative grid: 8 blocks/CU x 256 CU exactly

typedef unsigned short u16;
typedef unsigned int u32;
typedef __attribute__((ext_vector_type(8))) short short8;
typedef __attribute__((ext_vector_type(4))) float f32x4;

__device__ __forceinline__ float bf2f(u16 v) { return __uint_as_float(((u32)v) << 16); }
__device__ __forceinline__ u16 f2bf(float f) {
  __hip_bfloat16 h = __float2bfloat16(f);
  return *reinterpret_cast<u16*>(&h);
}
__device__ __forceinline__ float ldf(const void* p, long i, bool f32m) {
  return f32m ? ((const float*)p)[i] : bf2f(((const u16*)p)[i]);
}
__device__ __forceinline__ int edge_at(const void* eidx, long pos, bool i64) {
  return i64 ? (int)((const long long*)eidx)[pos] : ((const int*)eidx)[pos];
}

// deterministic local dtype detects (same fixed words in every block -> consistent)
__device__ __forceinline__ bool detect_i64(const u32* e32, int lane) {
  // int64 edges with values <50000 -> all odd u32 words zero
  return __ballot(e32[2 * lane + 1] != 0u) == 0ull;
}
__device__ __forceinline__ bool detect_f32(const u32* x32, int lane) {
  // f32 data: low u16 is random mantissa bits -> wild bf16 exponent
  u32 v = x32[lane] & 0xffffu;
  int e = (int)((v >> 7) & 0xff);
  bool wild = (v != 0u) && (e < 100 || e > 140);
  return __popcll(__ballot(wild)) > 16;
}

// ONE pre-kernel: blocks [0,SCATB) = XCD-partitioned padded-CSR scatter;
// blocks [SCATB, SCATB+3125) = x->bf16 (f32 mode) + MFMA B/proj frags + biases.
// The two halves are independent and run concurrently in one dispatch.
__global__ __launch_bounds__(256) void k_pre(
    const void* __restrict__ x, const void* __restrict__ eidx,
    const void* __restrict__ Wl, const void* __restrict__ bl,
    const void* __restrict__ Wr, const void* __restrict__ Wo,
    const void* __restrict__ bo,
    int* __restrict__ deg, u16* __restrict__ csr, u32* __restrict__ spill,
    u16* __restrict__ xA, u16* __restrict__ wfrag, u16* __restrict__ pfrag,
    float* __restrict__ blf, float* __restrict__ bof,
    int* __restrict__ flags) {
  int lane = threadIdx.x & 63;
  if (blockIdx.x < SCATB) {
    // ---- scatter: group g = blockIdx&7 owns dst range [g*PSZ,(g+1)*PSZ) ----
    bool i64 = detect_i64((const u32*)eidx, lane);
    int g = blockIdx.x & 7;
    int lo = g * PSZ, hi = lo + PSZ;
    int base = (blockIdx.x >> 3) * 256 + threadIdx.x;  // 0..65535 within group
    for (int e = base; e < NE; e += 65536) {
      int dst = edge_at(eidx, (long)NE + e, i64);
      if (dst >= lo && dst < hi) {
        int src = edge_at(eidx, e, i64);
        int pos = atomicAdd(&deg[dst], 1);
        if (pos < CAP) csr[(long)dst * CAP + pos] = (u16)src;
        else {
          int sp = atomicAdd(&flags[4], 1);
          spill[sp] = (u32)dst * 50000u + (u32)src;
        }
      }
    }
  } else {
    // ---- conversions ----
    bool f32m = detect_f32((const u32*)x, lane);
    int i = (blockIdx.x - SCATB) * 256 + threadIdx.x;  // 0..799999
    if (f32m) {
      float4 v = ((const float4*)x)[i];
      u32 lo = (u32)f2bf(v.x) | ((u32)f2bf(v.y) << 16);
      u32 hi = (u32)f2bf(v.z) | ((u32)f2bf(v.w) << 16);
      ((u32*)xA)[2 * i] = lo;
      ((u32*)xA)[2 * i + 1] = hi;
    }
    if (i < 3 * 16 * 64 * 8) {  // B frags: k=32s+(lane>>4)*8+j, n=16c+(lane&15)
      int j = i & 7, ln = (i >> 3) & 63, f = (i >> 9) & 15, l = i >> 13;
      int s = f >> 2, c = f & 3;
      int k = 32 * s + ((ln >> 4) << 3) + j;
      int n = (c << 4) + (ln & 15);
      long wbase = (long)l * HD * HD;
      float v = (k < HD) ? ldf(Wl, wbase + (long)k * HD + n, f32m)
                         : ldf(Wr, wbase + (long)(k - HD) * HD + n, f32m);
      wfrag[i] = f2bf(v);
    }
    if (i < 2 * 64 * 8) {  // proj frags
      int j = i & 7, ln = (i >> 3) & 63, s = i >> 9;
      int k = 32 * s + ((ln >> 4) << 3) + j;
      pfrag[i] = f2bf(ldf(Wo, (long)k * OD + (ln & 15), f32m));
    }
    if (i < 3 * HD) blf[i] = ldf(bl, i, f32m);
    if (i < OD) bof[i] = ldf(bo, i, f32m);
  }
}

// All 3 SAGE layers in ONE cooperative dispatch: grid-stride over 16-node
// tiles, grid.sync() between layers. Per-tile body identical to the previous
// k_fused (gather-mean -> 4x MFMA 16x16x32 -> relu -> store / fused proj).
// Launched with layer range [l0,l1): cooperative path uses (0,3); the
// fallback path launches (l,l+1) three times and never reaches grid.sync().
__global__ __launch_bounds__(256, 8) void k_layers(
    const u16* __restrict__ xbf, u16* __restrict__ xA, u16* __restrict__ xB,
    const u32* __restrict__ xorig32,
    const int* __restrict__ deg, const u16* __restrict__ csr,
    const u32* __restrict__ spill,
    const u16* __restrict__ wfrag, const u16* __restrict__ pfrag,
    const float* __restrict__ bl3, const float* __restrict__ bof,
    void* __restrict__ outp, const int* __restrict__ flags,
    int l0, int l1) {
  __shared__ __align__(16) u16 aw[16 * AST];
  __shared__ float sbl[HD];
  __shared__ float sbo[OD];
  int lane = threadIdx.x & 63;
  bool f32m = detect_f32(xorig32, lane);
  int spillcnt = __builtin_amdgcn_readfirstlane(flags[4]);
  int w = threadIdx.x >> 6;
  int fl = lane & 31;
  int half = lane >> 5;
  u32* aw32 = (u32*)aw;
  int quad = lane >> 4, m16 = lane & 15;
  if (threadIdx.x < OD) sbo[threadIdx.x] = bof[threadIdx.x];

  for (int layer = l0; layer < l1; ++layer) {
    const u16* xin = (layer == 0) ? (f32m ? xA : xbf)
                                  : ((layer == 1) ? (const u16*)xB : (const u16*)xA);
    u16* xout = (layer == 0) ? xB : ((layer == 1) ? xA : (u16*)0);
    int doProj = (layer == 2);
    const u32* x32 = (const u32*)xin;
    if (threadIdx.x < HD) sbl[threadIdx.x] = bl3[layer * HD + threadIdx.x];
    // sbl/sbo visibility is covered by the gather-phase __syncthreads below;
    // cross-layer reuse is separated by grid.sync().

    for (int tile = blockIdx.x; tile < TILES; tile += LGRID) {
      int nb = tile * 16;
      int n0 = nb + 4 * w;

      // ---- prefetch degrees (one 16B broadcast load) and all 4 csr rows ----
      int4 dv = *(const int4*)(deg + n0);
      int dt[4] = {__builtin_amdgcn_readfirstlane(dv.x),
                   __builtin_amdgcn_readfirstlane(dv.y),
                   __builtin_amdgcn_readfirstlane(dv.z),
                   __builtin_amdgcn_readfirstlane(dv.w)};
      int idx[4];
#pragma unroll
      for (int g = 0; g < 4; ++g) {
        int d = dt[g] < CAP ? dt[g] : CAP;
        idx[g] = (lane < d) ? (int)csr[(long)(n0 + g) * CAP + lane] : 0;
      }

      // ---- gather-mean: 16-neighbor chunks, 8 loads in flight ----
      for (int g = 0; g < 4; ++g) {
        int dtot = dt[g];
        int d = dtot < CAP ? dtot : CAP;
        float ax0 = 0.f, ay0 = 0.f, ax1 = 0.f, ay1 = 0.f;
        for (int j = 0; j < d; j += 16) {
          u32 v[8];
#pragma unroll
          for (int p = 0; p < 8; ++p) {
            int se = __builtin_amdgcn_readlane(idx[g], j + 2 * p);
            int so = __builtin_amdgcn_readlane(idx[g], j + 2 * p + 1);
            int s = half ? so : se;
            v[p] = x32[(long)s * 32 + fl];
          }
#pragma unroll
          for (int p = 0; p < 8; ++p) {
            int m = j + 2 * p + half;
            u32 vv = (m < d) ? v[p] : 0u;
            float vlo = __uint_as_float(vv << 16);
            float vhi = __uint_as_float(vv & 0xffff0000u);
            if (p & 1) { ax1 += vlo; ay1 += vhi; }
            else       { ax0 += vlo; ay0 += vhi; }
          }
        }
        float ax = ax0 + ax1, ay = ay0 + ay1;
        ax += __shfl_xor(ax, 32);
        ay += __shfl_xor(ay, 32);
        if (spillcnt > 0) {  // cold path: only if some node exceeded CAP
          int n = n0 + g;
          for (int base = 0; base < spillcnt; base += 64) {
            u32 p = (base + lane < spillcnt) ? spill[base + lane] : 0xffffffffu;
            u32 dd = p / 50000u;
            u32 ss = p - dd * 50000u;
            unsigned long long mk = __ballot(dd == (u32)n);
            while (mk) {
              int j = __builtin_ctzll(mk);
              mk &= mk - 1;
              int s = __builtin_amdgcn_readlane((int)ss, j);
              u32 v = x32[(long)s * 32 + fl];
              ax += __uint_as_float(v << 16);
              ay += __uint_as_float(v & 0xffff0000u);
            }
          }
        }
        float rd = 1.0f / (float)(dtot > 0 ? dtot : 1);
        if (half == 0)  // lane fl holds features 2fl, 2fl+1
          aw32[(4 * w + g) * (AST / 2) + fl] =
              (u32)f2bf(ax * rd) | ((u32)f2bf(ay * rd) << 16);
      }
      __syncthreads();

      // ---- A fragments (shared tile), B fragments straight from global ----
      short8 a0 = *(const short8*)(aw + m16 * AST + quad * 8);        // k 0..31
      short8 a1 = *(const short8*)(aw + m16 * AST + 32 + quad * 8);   // k 32..63
      const u16* xrow = xin + (long)(nb + m16) * HD;
      short8 x2 = *(const short8*)(xrow + quad * 8);                  // k 64..95
      short8 x3 = *(const short8*)(xrow + 32 + quad * 8);             // k 96..127
      int c = w;  // this wave's col-tile
      const short8* bp = (const short8*)(wfrag + (long)layer * 16 * 64 * 8);
      short8 b0 = bp[(0 * 4 + c) * 64 + lane];
      short8 b1 = bp[(1 * 4 + c) * 64 + lane];
      short8 b2 = bp[(2 * 4 + c) * 64 + lane];
      short8 b3 = bp[(3 * 4 + c) * 64 + lane];
      float bb = sbl[c * 16 + m16];
      f32x4 acc = (f32x4){bb, bb, bb, bb};
      acc = __builtin_amdgcn_mfma_f32_16x16x32_bf16(a0, b0, acc, 0, 0, 0);
      acc = __builtin_amdgcn_mfma_f32_16x16x32_bf16(a1, b1, acc, 0, 0, 0);
      acc = __builtin_amdgcn_mfma_f32_16x16x32_bf16(x2, b2, acc, 0, 0, 0);
      acc = __builtin_amdgcn_mfma_f32_16x16x32_bf16(x3, b3, acc, 0, 0, 0);
      __syncthreads();  // all A reads done before C overwrites aw

      // ---- relu -> C staging (C layout: col=lane&15, row=quad*4+reg) ----
#pragma unroll
      for (int r = 0; r < 4; ++r)
        aw[(quad * 4 + r) * AST + c * 16 + m16] = f2bf(fmaxf(acc[r], 0.f));
      __syncthreads();

      if (!doProj) {
        // coalesced tile store: thread covers 8 B; row = tid>>4, chunk = tid&15
        int row = threadIdx.x >> 4, ch = threadIdx.x & 15;
        uint2 vv = *(const uint2*)(aw + row * AST + ch * 4);
        *(uint2*)(xout + (long)(nb + row) * HD + ch * 4) = vv;
      } else if (w == 0) {
        // projection: relu_tile [16x64] @ Wo [64x16] + bo
        short8 pa0 = *(const short8*)(aw + m16 * AST + quad * 8);
        short8 pa1 = *(const short8*)(aw + m16 * AST + 32 + quad * 8);
        const short8* pb = (const short8*)pfrag;
        short8 pb0 = pb[lane];
        short8 pb1 = pb[64 + lane];
        float bv = sbo[m16];
        f32x4 pacc = (f32x4){bv, bv, bv, bv};
        pacc = __builtin_amdgcn_mfma_f32_16x16x32_bf16(pa0, pb0, pacc, 0, 0, 0);
        pacc = __builtin_amdgcn_mfma_f32_16x16x32_bf16(pa1, pb1, pacc, 0, 0, 0);
        if (f32m) {
          float* o = (float*)outp;
#pragma unroll
          for (int r = 0; r < 4; ++r)
            o[(long)(nb + quad * 4 + r) * OD + m16] = pacc[r];
        } else {
          u16* o = (u16*)outp;
#pragma unroll
          for (int r = 0; r < 4; ++r)
            o[(long)(nb + quad * 4 + r) * OD + m16] = f2bf(pacc[r]);
        }
      }
      __syncthreads();  // aw reused by next tile's gather
    }
    if (layer + 1 < l1) cg::this_grid().sync();
  }
}

extern "C" void kernel_launch(void* const* d_in, const int* in_sizes, int n_in,
                              void* d_out, int out_size, void* d_ws, size_t ws_size,
                              hipStream_t stream) {
  const void* x = d_in[0];
  const void* eidx = d_in[1];
  const void* Wl = d_in[2];
  const void* bl = d_in[3];
  const void* Wr = d_in[4];
  const void* Wo = d_in[5];
  const void* bo = d_in[6];

  char* w = (char*)d_ws;
  size_t off = 0;
  int* flags = (int*)(w + off);     off += 256;   // [4]=spillcnt
  int* deg = (int*)(w + off);       off += (size_t)NN * 4 + 192;
  size_t memset_bytes = off;                      // one memset: flags+deg
  u16* csr = (u16*)(w + off);       off += (size_t)NN * CAP * 2;   // 6.4 MB
  u32* spill = (u32*)(w + off);     off += (size_t)NE * 4;         // 3.2 MB
  u16* wfrag = (u16*)(w + off);     off += 3 * 16 * 64 * 8 * 2;
  u16* pfrag = (u16*)(w + off);     off += 2 * 64 * 8 * 2;
  float* blf = (float*)(w + off);   off += 3 * HD * 4;
  float* bof = (float*)(w + off);   off += 256;
  u16* xA = (u16*)(w + off);        off += (size_t)NN * HD * 2;
  u16* xB = (u16*)(w + off);        off += (size_t)NN * HD * 2;

  hipMemsetAsync(flags, 0, memset_bytes, stream);

  k_pre<<<SCATB + 3125, 256, 0, stream>>>(x, eidx, Wl, bl, Wr, Wo, bo,
                                          deg, csr, spill, xA, wfrag, pfrag,
                                          blf, bof, flags);

  const u16* xbf = (const u16*)x;
  const u32* xo32 = (const u32*)x;
  void* outp = d_out;
  int l0 = 0, l1 = 3;
  void* kargs[] = {(void*)&xbf, (void*)&xA, (void*)&xB, (void*)&xo32,
                   (void*)&deg, (void*)&csr, (void*)&spill, (void*)&wfrag,
                   (void*)&pfrag, (void*)&blf, (void*)&bof, (void*)&outp,
                   (void*)&flags, (void*)&l0, (void*)&l1};
  hipError_t ce = hipLaunchCooperativeKernel((void*)k_layers, dim3(LGRID),
                                             dim3(256), kargs, 0, stream);
  if (ce != hipSuccess) {
    // fallback: 3 normal launches; grid.sync() is dynamically unreachable
    for (int l = 0; l < 3; ++l)
      k_layers<<<LGRID, 256, 0, stream>>>(xbf, xA, xB, xo32, deg, csr, spill,
                                          wfrag, pfrag, blf, bof, outp, flags,
                                          l, l + 1);
  }
}

// Round 2
// 175.687 us; speedup vs baseline: 4.1204x; 4.1204x over previous
//
#include <hip/hip_runtime.h>
#include <hip/hip_bf16.h>

#define NN 50000
#define NE 800000
#define HD 64
#define OD 16
#define CAP 64        // padded-CSR slots per node (mean deg = 16; P(>64) ~ 1e-18)
#define TILES 3125    // NN/16
#define AST 72        // LDS A/C row stride in u16 (144 B); 36 u32
#define SCATB 2048    // scatter blocks in k_pre
#define PSZ 6250      // NN / 8 partitions

typedef unsigned short u16;
typedef unsigned int u32;
typedef __attribute__((ext_vector_type(8))) short short8;
typedef __attribute__((ext_vector_type(4))) float f32x4;

__device__ __forceinline__ float bf2f(u16 v) { return __uint_as_float(((u32)v) << 16); }
__device__ __forceinline__ u16 f2bf(float f) {
  __hip_bfloat16 h = __float2bfloat16(f);
  return *reinterpret_cast<u16*>(&h);
}
__device__ __forceinline__ float ldf(const void* p, long i, bool f32m) {
  return f32m ? ((const float*)p)[i] : bf2f(((const u16*)p)[i]);
}
__device__ __forceinline__ int edge_at(const void* eidx, long pos, bool i64) {
  return i64 ? (int)((const long long*)eidx)[pos] : ((const int*)eidx)[pos];
}

// deterministic local dtype detects (same fixed words in every block -> consistent)
__device__ __forceinline__ bool detect_i64(const u32* e32, int lane) {
  // int64 edges with values <50000 -> all odd u32 words zero
  return __ballot(e32[2 * lane + 1] != 0u) == 0ull;
}
__device__ __forceinline__ bool detect_f32(const u32* x32, int lane) {
  // f32 data: low u16 is random mantissa bits -> wild bf16 exponent
  u32 v = x32[lane] & 0xffffu;
  int e = (int)((v >> 7) & 0xff);
  bool wild = (v != 0u) && (e < 100 || e > 140);
  return __popcll(__ballot(wild)) > 16;
}

// ONE pre-kernel: blocks [0,SCATB) = XCD-partitioned padded-CSR scatter;
// blocks [SCATB, SCATB+3125) = x->bf16 (f32 mode) + MFMA B/proj frags + biases.
__global__ __launch_bounds__(256) void k_pre(
    const void* __restrict__ x, const void* __restrict__ eidx,
    const void* __restrict__ Wl, const void* __restrict__ bl,
    const void* __restrict__ Wr, const void* __restrict__ Wo,
    const void* __restrict__ bo,
    int* __restrict__ deg, u16* __restrict__ csr, u32* __restrict__ spill,
    u16* __restrict__ xA, u16* __restrict__ wfrag, u16* __restrict__ pfrag,
    float* __restrict__ blf, float* __restrict__ bof,
    int* __restrict__ flags) {
  int lane = threadIdx.x & 63;
  if (blockIdx.x < SCATB) {
    // ---- scatter: group g = blockIdx&7 owns dst range [g*PSZ,(g+1)*PSZ) ----
    bool i64 = detect_i64((const u32*)eidx, lane);
    int g = blockIdx.x & 7;
    int lo = g * PSZ, hi = lo + PSZ;
    int base = (blockIdx.x >> 3) * 256 + threadIdx.x;  // 0..65535 within group
    for (int e = base; e < NE; e += 65536) {
      int dst = edge_at(eidx, (long)NE + e, i64);
      if (dst >= lo && dst < hi) {
        int src = edge_at(eidx, e, i64);
        int pos = atomicAdd(&deg[dst], 1);
        if (pos < CAP) csr[(long)dst * CAP + pos] = (u16)src;
        else {
          int sp = atomicAdd(&flags[4], 1);
          spill[sp] = (u32)dst * 50000u + (u32)src;
        }
      }
    }
  } else {
    // ---- conversions ----
    bool f32m = detect_f32((const u32*)x, lane);
    int i = (blockIdx.x - SCATB) * 256 + threadIdx.x;  // 0..799999
    if (f32m) {
      float4 v = ((const float4*)x)[i];
      u32 lo = (u32)f2bf(v.x) | ((u32)f2bf(v.y) << 16);
      u32 hi = (u32)f2bf(v.z) | ((u32)f2bf(v.w) << 16);
      ((u32*)xA)[2 * i] = lo;
      ((u32*)xA)[2 * i + 1] = hi;
    }
    if (i < 3 * 16 * 64 * 8) {  // B frags: k=32s+(lane>>4)*8+j, n=16c+(lane&15)
      int j = i & 7, ln = (i >> 3) & 63, f = (i >> 9) & 15, l = i >> 13;
      int s = f >> 2, c = f & 3;
      int k = 32 * s + ((ln >> 4) << 3) + j;
      int n = (c << 4) + (ln & 15);
      long wbase = (long)l * HD * HD;
      float v = (k < HD) ? ldf(Wl, wbase + (long)k * HD + n, f32m)
                         : ldf(Wr, wbase + (long)(k - HD) * HD + n, f32m);
      wfrag[i] = f2bf(v);
    }
    if (i < 2 * 64 * 8) {  // proj frags
      int j = i & 7, ln = (i >> 3) & 63, s = i >> 9;
      int k = 32 * s + ((ln >> 4) << 3) + j;
      pfrag[i] = f2bf(ldf(Wo, (long)k * OD + (ln & 15), f32m));
    }
    if (i < 3 * HD) blf[i] = ldf(bl, i, f32m);
    if (i < OD) bof[i] = ldf(bo, i, f32m);
  }
}

// fused SAGE layer: block = 4 waves = ONE 16-node tile.
// Gather v2: quarter-split dwordx2 loads (16 lanes x 8B = one 128B node row),
// 8 insts cover 32 neighbors; 2-node-deep pipeline keeps 16 loads in flight.
// Neighbor ids come from ONE dwordx2 CSR load (all 4 rows) via readlane +
// per-lane sub-u16 select. Garbage CSR slots clamped to [0,NN) and predicated.
__global__ __launch_bounds__(256, 8) void k_fused(
    const u16* __restrict__ xin_bf, const u16* __restrict__ xin_f32m,
    const u32* __restrict__ xorig32, u16* __restrict__ xout,
    const int* __restrict__ deg, const u16* __restrict__ csr,
    const u32* __restrict__ spill,
    const u16* __restrict__ wfrag, const u16* __restrict__ pfrag,
    const float* __restrict__ bl3, const float* __restrict__ bof,
    void* __restrict__ outp, int layer, int doProj,
    const int* __restrict__ flags) {
  __shared__ __align__(16) u16 aw[16 * AST];
  __shared__ float sbl[HD];
  __shared__ float sbo[OD];
  if (threadIdx.x < HD) sbl[threadIdx.x] = bl3[layer * HD + threadIdx.x];
  if (threadIdx.x < OD) sbo[threadIdx.x] = bof[threadIdx.x];
  int lane = threadIdx.x & 63;
  bool f32m = detect_f32(xorig32, lane);
  int spillcnt = __builtin_amdgcn_readfirstlane(flags[4]);
  const u16* xin = f32m ? xin_f32m : xin_bf;
  const uint2* x2p = (const uint2*)xin;

  int w = threadIdx.x >> 6;
  int nb = blockIdx.x * 16;
  int q = lane >> 4;        // quarter 0..3: neighbor-within-inst
  int f = lane & 15;        // 8B feature group: features 4f..4f+3
  u32* aw32 = (u32*)aw;
  int n0 = nb + 4 * w;

  // ---- degrees (one 16B broadcast load) + ALL 4 csr rows in ONE dwordx2 ----
  int4 dv = *(const int4*)(deg + n0);
  int dt[4] = {__builtin_amdgcn_readfirstlane(dv.x),
               __builtin_amdgcn_readfirstlane(dv.y),
               __builtin_amdgcn_readfirstlane(dv.z),
               __builtin_amdgcn_readfirstlane(dv.w)};
  // lane l holds csr u16 slots 4l..4l+3 of the 4x64-slot block
  uint2 cidx = ((const uint2*)(csr + (long)n0 * CAP))[lane];

  // issue one 8-inst batch (32 neighbors) for node gg, chunk base jj (mult of 4)
#define LOADB(dst, gg, jj)                                                    \
  do {                                                                        \
    _Pragma("unroll") for (int p = 0; p < 8; ++p) {                           \
      u32 wx = (u32)__builtin_amdgcn_readlane((int)cidx.x,                    \
                                              (gg)*16 + ((jj) >> 2) + p);     \
      u32 wy = (u32)__builtin_amdgcn_readlane((int)cidx.y,                    \
                                              (gg)*16 + ((jj) >> 2) + p);     \
      u32 ww = (q & 2) ? wy : wx;                                             \
      int s = (int)((ww >> ((q & 1) * 16)) & 0xffffu);                        \
      s = s < NN ? s : 0;  /* clamp garbage slots; predicated at consume */   \
      dst[p] = x2p[(long)s * 16 + f];                                         \
    }                                                                         \
  } while (0)

  // consume batch for node gg: predicate, accumulate, (rare tail), reduce, store
#define CONSB(vv, gg)                                                         \
  do {                                                                        \
    int dtot = dt[gg];                                                        \
    int d = dtot < CAP ? dtot : CAP;                                          \
    float a0 = 0.f, a1 = 0.f, a2 = 0.f, a3 = 0.f;                             \
    _Pragma("unroll") for (int p = 0; p < 8; ++p) {                           \
      bool val = (4 * p + q) < d;                                             \
      u32 lo = val ? (u32)vv[p].x : 0u;                                       \
      u32 hi = val ? (u32)vv[p].y : 0u;                                       \
      a0 += __uint_as_float(lo << 16);                                        \
      a1 += __uint_as_float(lo & 0xffff0000u);                                \
      a2 += __uint_as_float(hi << 16);                                        \
      a3 += __uint_as_float(hi & 0xffff0000u);                                \
    }                                                                         \
    if (d > 32) { /* uniform branch; ~0.01% of nodes */                       \
      _Pragma("unroll") for (int p = 0; p < 8; ++p) {                         \
        u32 wx = (u32)__builtin_amdgcn_readlane((int)cidx.x, (gg)*16 + 8 + p);\
        u32 wy = (u32)__builtin_amdgcn_readlane((int)cidx.y, (gg)*16 + 8 + p);\
        u32 ww = (q & 2) ? wy : wx;                                           \
        int s = (int)((ww >> ((q & 1) * 16)) & 0xffffu);                      \
        s = s < NN ? s : 0;                                                   \
        uint2 t = x2p[(long)s * 16 + f];                                      \
        bool val = (32 + 4 * p + q) < d;                                      \
        u32 lo = val ? (u32)t.x : 0u;                                         \
        u32 hi = val ? (u32)t.y : 0u;                                         \
        a0 += __uint_as_float(lo << 16);                                      \
        a1 += __uint_as_float(lo & 0xffff0000u);                              \
        a2 += __uint_as_float(hi << 16);                                      \
        a3 += __uint_as_float(hi & 0xffff0000u);                              \
      }                                                                       \
    }                                                                         \
    a0 += __shfl_xor(a0, 16); a1 += __shfl_xor(a1, 16);                       \
    a2 += __shfl_xor(a2, 16); a3 += __shfl_xor(a3, 16);                       \
    a0 += __shfl_xor(a0, 32); a1 += __shfl_xor(a1, 32);                       \
    a2 += __shfl_xor(a2, 32); a3 += __shfl_xor(a3, 32);                       \
    if (spillcnt > 0) { /* cold path: only if some node exceeded CAP */       \
      int n = n0 + (gg);                                                      \
      for (int base = 0; base < spillcnt; base += 64) {                       \
        u32 pp = (base + lane < spillcnt) ? spill[base + lane] : 0xffffffffu; \
        u32 dd = pp / 50000u;                                                 \
        u32 ss = pp - dd * 50000u;                                            \
        unsigned long long mk = __ballot(dd == (u32)n);                       \
        while (mk) {                                                          \
          int j = __builtin_ctzll(mk);                                        \
          mk &= mk - 1;                                                       \
          int s = __builtin_amdgcn_readlane((int)ss, j);                      \
          uint2 t = x2p[(long)s * 16 + f];                                    \
          a0 += __uint_as_float(((u32)t.x) << 16);                            \
          a1 += __uint_as_float(((u32)t.x) & 0xffff0000u);                    \
          a2 += __uint_as_float(((u32)t.y) << 16);                            \
          a3 += __uint_as_float(((u32)t.y) & 0xffff0000u);                    \
        }                                                                     \
      }                                                                       \
    }                                                                         \
    float rd = 1.0f / (float)(dtot > 0 ? dtot : 1);                           \
    if (q == 0) { /* lane f stores features 4f..4f+3 */                       \
      u32 plo = (u32)f2bf(a0 * rd) | ((u32)f2bf(a1 * rd) << 16);              \
      u32 phi = (u32)f2bf(a2 * rd) | ((u32)f2bf(a3 * rd) << 16);              \
      *(uint2*)(aw32 + (4 * w + (gg)) * (AST / 2) + 2 * f) =                  \
          make_uint2(plo, phi);                                               \
    }                                                                         \
  } while (0)

  // ---- 2-node-deep pipelined gather-mean: 16 loads in flight ----
  {
    uint2 va[8], vb[8];
    LOADB(va, 0, 0);
    LOADB(vb, 1, 0);
    CONSB(va, 0);
    LOADB(va, 2, 0);
    CONSB(vb, 1);
    LOADB(vb, 3, 0);
    CONSB(va, 2);
    CONSB(vb, 3);
  }
#undef LOADB
#undef CONSB
  __syncthreads();

  // ---- A fragments (shared tile), B fragments straight from global ----
  int quad = lane >> 4, m16 = lane & 15;
  short8 a0 = *(const short8*)(aw + m16 * AST + quad * 8);        // k 0..31
  short8 a1 = *(const short8*)(aw + m16 * AST + 32 + quad * 8);   // k 32..63
  const u16* xrow = xin + (long)(nb + m16) * HD;
  short8 x2 = *(const short8*)(xrow + quad * 8);                  // k 64..95
  short8 x3 = *(const short8*)(xrow + 32 + quad * 8);             // k 96..127
  int c = w;  // this wave's col-tile
  const short8* bp = (const short8*)(wfrag + (long)layer * 16 * 64 * 8);
  short8 b0 = bp[(0 * 4 + c) * 64 + lane];
  short8 b1 = bp[(1 * 4 + c) * 64 + lane];
  short8 b2 = bp[(2 * 4 + c) * 64 + lane];
  short8 b3 = bp[(3 * 4 + c) * 64 + lane];
  float bb = sbl[c * 16 + m16];
  f32x4 acc = (f32x4){bb, bb, bb, bb};
  acc = __builtin_amdgcn_mfma_f32_16x16x32_bf16(a0, b0, acc, 0, 0, 0);
  acc = __builtin_amdgcn_mfma_f32_16x16x32_bf16(a1, b1, acc, 0, 0, 0);
  acc = __builtin_amdgcn_mfma_f32_16x16x32_bf16(x2, b2, acc, 0, 0, 0);
  acc = __builtin_amdgcn_mfma_f32_16x16x32_bf16(x3, b3, acc, 0, 0, 0);
  __syncthreads();  // all A reads done before C overwrites aw

  // ---- relu -> C staging (C layout: col=lane&15, row=quad*4+reg) ----
#pragma unroll
  for (int r = 0; r < 4; ++r)
    aw[(quad * 4 + r) * AST + c * 16 + m16] = f2bf(fmaxf(acc[r], 0.f));
  __syncthreads();

  if (!doProj) {
    // coalesced tile store: thread covers 8 B; row = tid>>4, chunk = tid&15
    int row = threadIdx.x >> 4, ch = threadIdx.x & 15;
    uint2 v = *(const uint2*)(aw + row * AST + ch * 4);
    *(uint2*)(xout + (long)(nb + row) * HD + ch * 4) = v;
  } else if (w == 0) {
    // projection: relu_tile [16x64] @ Wo [64x16] + bo
    short8 pa0 = *(const short8*)(aw + m16 * AST + quad * 8);
    short8 pa1 = *(const short8*)(aw + m16 * AST + 32 + quad * 8);
    const short8* pb = (const short8*)pfrag;
    short8 pb0 = pb[lane];
    short8 pb1 = pb[64 + lane];
    float bv = sbo[m16];
    f32x4 pacc = (f32x4){bv, bv, bv, bv};
    pacc = __builtin_amdgcn_mfma_f32_16x16x32_bf16(pa0, pb0, pacc, 0, 0, 0);
    pacc = __builtin_amdgcn_mfma_f32_16x16x32_bf16(pa1, pb1, pacc, 0, 0, 0);
    if (f32m) {
      float* o = (float*)outp;
#pragma unroll
      for (int r = 0; r < 4; ++r)
        o[(long)(nb + quad * 4 + r) * OD + m16] = pacc[r];
    } else {
      u16* o = (u16*)outp;
#pragma unroll
      for (int r = 0; r < 4; ++r)
        o[(long)(nb + quad * 4 + r) * OD + m16] = f2bf(pacc[r]);
    }
  }
}

extern "C" void kernel_launch(void* const* d_in, const int* in_sizes, int n_in,
                              void* d_out, int out_size, void* d_ws, size_t ws_size,
                              hipStream_t stream) {
  const void* x = d_in[0];
  const void* eidx = d_in[1];
  const void* Wl = d_in[2];
  const void* bl = d_in[3];
  const void* Wr = d_in[4];
  const void* Wo = d_in[5];
  const void* bo = d_in[6];

  char* w = (char*)d_ws;
  size_t off = 0;
  int* flags = (int*)(w + off);     off += 256;   // [4]=spillcnt
  int* deg = (int*)(w + off);       off += (size_t)NN * 4 + 192;
  size_t memset_bytes = off;                      // one memset: flags+deg
  u16* csr = (u16*)(w + off);       off += (size_t)NN * CAP * 2;   // 6.4 MB
  u32* spill = (u32*)(w + off);     off += (size_t)NE * 4;         // 3.2 MB
  u16* wfrag = (u16*)(w + off);     off += 3 * 16 * 64 * 8 * 2;
  u16* pfrag = (u16*)(w + off);     off += 2 * 64 * 8 * 2;
  float* blf = (float*)(w + off);   off += 3 * HD * 4;
  float* bof = (float*)(w + off);   off += 256;
  u16* xA = (u16*)(w + off);        off += (size_t)NN * HD * 2;
  u16* xB = (u16*)(w + off);        off += (size_t)NN * HD * 2;

  hipMemsetAsync(flags, 0, memset_bytes, stream);

  k_pre<<<SCATB + 3125, 256, 0, stream>>>(x, eidx, Wl, bl, Wr, Wo, bo,
                                          deg, csr, spill, xA, wfrag, pfrag,
                                          blf, bof, flags);

  const u32* xo32 = (const u32*)x;
  // L0: (x|xA) -> xB ; L1: xB -> xA ; L2: xA -> d_out (fused projection)
  k_fused<<<TILES, 256, 0, stream>>>((const u16*)x, xA, xo32, xB, deg, csr, spill,
                                     wfrag, pfrag, blf, bof, (void*)0, 0, 0, flags);
  k_fused<<<TILES, 256, 0, stream>>>(xB, xB, xo32, xA, deg, csr, spill,
                                     wfrag, pfrag, blf, bof, (void*)0, 1, 0, flags);
  k_fused<<<TILES, 256, 0, stream>>>(xA, xA, xo32, (u16*)0, deg, csr, spill,
                                     wfrag, pfrag, blf, bof, d_out, 2, 1, flags);
}